// Round 9
// baseline (1021.679 us; speedup 1.0000x reference)
//
#include <hip/hip_runtime.h>
#include <stdint.h>
#include <stddef.h>

typedef __attribute__((ext_vector_type(8))) short short8;
typedef __attribute__((ext_vector_type(4))) float f32x4;
typedef __attribute__((ext_vector_type(4))) int i32x4;

#define T_DIM 8192
#define M_DIM 4096
#define K_DIM 4096

// f32 -> bf16 round-to-nearest-even (fallback path only)
__device__ __forceinline__ unsigned short f2b(float f) {
    unsigned int u = __builtin_bit_cast(unsigned int, f);
    u += 0x7fffu + ((u >> 16) & 1u);
    return (unsigned short)(u >> 16);
}

__device__ __forceinline__ void async_copy16(const void* g, const void* l) {
    __builtin_amdgcn_global_load_lds(
        (const __attribute__((address_space(1))) unsigned int*)g,
        (__attribute__((address_space(3))) unsigned int*)l,
        16, 0, 0);
}

// ---------------------------------------------------------------------------
// prep_w: dequant w -> qw (f32, exact reference path) + wq (int8 = rint(lut*127))
// ---------------------------------------------------------------------------
__global__ void prep_w(const float* __restrict__ w,
                       const float* __restrict__ maxval,
                       const float* __restrict__ lut_g,
                       float* __restrict__ qw,
                       signed char* __restrict__ wq) {
    __shared__ float lut[16];
    if (threadIdx.x < 16) lut[threadIdx.x] = lut_g[threadIdx.x];
    __syncthreads();

    size_t base = ((size_t)blockIdx.x * 256 + threadIdx.x) * 8;
    float mv = maxval[base >> 6];

    float4 w0 = *reinterpret_cast<const float4*>(w + base);
    float4 w1 = *reinterpret_cast<const float4*>(w + base + 4);
    float vin[8] = {w0.x, w0.y, w0.z, w0.w, w1.x, w1.y, w1.z, w1.w};
    float outv[8];
    int   qi[8];

    #pragma unroll
    for (int e = 0; e < 8; ++e) {
        float v = vin[e] / mv;
        float bd = fabsf(v - lut[0]);
        int best = 0;
        #pragma unroll
        for (int k = 1; k < 16; ++k) {
            float d = fabsf(v - lut[k]);
            if (d < bd) { bd = d; best = k; }
        }
        outv[e] = lut[best] * mv;
        qi[e]   = (int)rintf(lut[best] * 127.0f);
    }

    float4 o0; o0.x = outv[0]; o0.y = outv[1]; o0.z = outv[2]; o0.w = outv[3];
    float4 o1; o1.x = outv[4]; o1.y = outv[5]; o1.z = outv[6]; o1.w = outv[7];
    *reinterpret_cast<float4*>(qw + base)     = o0;
    *reinterpret_cast<float4*>(qw + base + 4) = o1;

    if (wq != nullptr) {
        unsigned u0 = 0, u1 = 0;
        #pragma unroll
        for (int e = 0; e < 4; ++e) u0 |= ((unsigned)(qi[e] & 255)) << (8 * e);
        #pragma unroll
        for (int e = 0; e < 4; ++e) u1 |= ((unsigned)(qi[4 + e] & 255)) << (8 * e);
        uint2 pk; pk.x = u0; pk.y = u1;
        *reinterpret_cast<uint2*>(wq + base) = pk;
    }
}

// ---------------------------------------------------------------------------
// prep_x: per-row quantize x -> int8 with scale rowmax/127; sx[row]=rowmax/127^2
// one block (512 thr) per row of 4096.
// ---------------------------------------------------------------------------
__global__ __launch_bounds__(512) void prep_x(const float* __restrict__ x,
                                              signed char* __restrict__ xq,
                                              float* __restrict__ sx) {
    const int row = blockIdx.x;
    const int tid = threadIdx.x;
    const float* xr = x + (size_t)row * K_DIM;

    float4 a = *reinterpret_cast<const float4*>(xr + tid * 8);
    float4 b = *reinterpret_cast<const float4*>(xr + tid * 8 + 4);
    float v[8] = {a.x, a.y, a.z, a.w, b.x, b.y, b.z, b.w};

    float mx = 0.0f;
    #pragma unroll
    for (int e = 0; e < 8; ++e) mx = fmaxf(mx, fabsf(v[e]));
    #pragma unroll
    for (int off = 1; off < 64; off <<= 1)
        mx = fmaxf(mx, __shfl_xor(mx, off, 64));

    __shared__ float wm[8];
    if ((tid & 63) == 0) wm[tid >> 6] = mx;
    __syncthreads();
    float rmax = fmaxf(fmaxf(fmaxf(wm[0], wm[1]), fmaxf(wm[2], wm[3])),
                       fmaxf(fmaxf(wm[4], wm[5]), fmaxf(wm[6], wm[7])));
    float inv = rmax > 0.0f ? 127.0f / rmax : 0.0f;

    unsigned u0 = 0, u1 = 0;
    #pragma unroll
    for (int e = 0; e < 4; ++e) {
        int q = (int)rintf(v[e] * inv);
        q = q > 127 ? 127 : (q < -127 ? -127 : q);
        u0 |= ((unsigned)(q & 255)) << (8 * e);
    }
    #pragma unroll
    for (int e = 0; e < 4; ++e) {
        int q = (int)rintf(v[4 + e] * inv);
        q = q > 127 ? 127 : (q < -127 ? -127 : q);
        u1 |= ((unsigned)(q & 255)) << (8 * e);
    }
    uint2 pk; pk.x = u0; pk.y = u1;
    *reinterpret_cast<uint2*>(xq + (size_t)row * K_DIM + tid * 8) = pk;

    if (tid == 0) sx[row] = rmax / 16129.0f;   // rowmax / 127^2
}

// mvT[t*4096 + m] = mv[m*64 + t]  (t = K-tile index 0..63)
__global__ void mvt_kernel(const float* __restrict__ mv, float* __restrict__ mvT) {
    int id = blockIdx.x * 256 + threadIdx.x;      // 64*4096 = 262144
    int t = id >> 12, m = id & 4095;
    mvT[id] = mv[m * 64 + t];
}

// ---------------------------------------------------------------------------
// i8 256x256 GEMM, R7 schedule (4 phases, single barrier, vmcnt-counted):
//   accf[t][m] += mv[m,kb] * (Σ_{k in kb} xq*wq);  y = accf * sx[t]
// 8 waves (2Mx4N), BK=64 = exactly one weight scale block, LDS 64KB dbuf.
// Regions per buffer (8 KiB): r0=A(MH0) r1=B(NH1) r2=A(MH1) r3=B(NH0).
// Fragment: mfma_i32_16x16x64_i8, lane holds 16 K-consecutive i8 at
// k0=(lane>>4)*16 (analogy to verified bf16 16x16x32 pattern).
// LDS swizzle (64B rows): slot = q ^ ((row>>1)&3); verified conflict-free
// (8-consecutive-lane groups hit 8 distinct 16B slots).
// Scales: mvT row per tile, prefetched at P2 into ping-pong swA/swB.
// vmcnt(3) at P3 (1 instr per staging seq) == R7's vmcnt(6) with 2-instr seqs.
// ---------------------------------------------------------------------------

#define RD_A8(BUF, MH)                                                        \
  { _Pragma("unroll") for (int mi = 0; mi < 4; ++mi) {                        \
        int r_ = wr * 64 + mi * 16 + fr;                                      \
        aI[mi] = *reinterpret_cast<const i32x4*>(                             \
            lds + (BUF) * 32768 + (MH) * 16384 + r_ * 64 +                    \
            (fkB ^ (((r_ >> 1) & 3) << 4)));                                  \
  } }

#define RD_B8(BUF, NH, DST)                                                   \
  { _Pragma("unroll") for (int ni = 0; ni < 2; ++ni) {                        \
        int r_ = wc * 32 + ni * 16 + fr;                                      \
        DST[ni] = *reinterpret_cast<const i32x4*>(                            \
            lds + (BUF) * 32768 + ((NH) ? 8192 : 24576) + r_ * 64 +           \
            (fkB ^ (((r_ >> 1) & 3) << 4)));                                  \
  } }

#define PHASE8(BUF, MH, NH, DO_A, DO_B0, DO_B1, SW, SCLDST, SCLT, VM)         \
  {                                                                           \
    if (DO_A)  RD_A8(BUF, MH)                                                 \
    if (DO_B0) RD_B8(BUF, 0, bI0)                                             \
    if (DO_B1) RD_B8(BUF, 1, bI1)                                             \
    if ((SCLT) >= 0) {                                                        \
        int tt = (SCLT) < 63 ? (SCLT) : 63;                                   \
        _Pragma("unroll") for (int ni = 0; ni < 4; ++ni)                      \
            SCLDST[ni] = mvp[(size_t)tt * 4096 + ni * 16];                    \
    }                                                                         \
    issue_seq(seq); ++seq;                                                    \
    asm volatile("" ::: "memory");                                            \
    __builtin_amdgcn_s_barrier();                                             \
    asm volatile("" ::: "memory");                                            \
    __builtin_amdgcn_s_setprio(1);                                            \
    _Pragma("unroll") for (int mi = 0; mi < 4; ++mi)                          \
    _Pragma("unroll") for (int ni = 0; ni < 2; ++ni) {                        \
        i32x4 d = __builtin_amdgcn_mfma_i32_16x16x64_i8(                      \
            aI[mi], (NH) ? bI1[ni] : bI0[ni], zero4, 0, 0, 0);                \
        const float s_ = SW[(NH) * 2 + ni];                                   \
        accf[(MH) * 4 + mi][(NH) * 2 + ni][0] += s_ * (float)d[0];            \
        accf[(MH) * 4 + mi][(NH) * 2 + ni][1] += s_ * (float)d[1];            \
        accf[(MH) * 4 + mi][(NH) * 2 + ni][2] += s_ * (float)d[2];            \
        accf[(MH) * 4 + mi][(NH) * 2 + ni][3] += s_ * (float)d[3];            \
    }                                                                         \
    __builtin_amdgcn_s_setprio(0);                                            \
    if (VM) asm volatile("s_waitcnt vmcnt(3)" ::: "memory");                  \
  }

__global__ __launch_bounds__(512, 2) void gemm_i8(
    const signed char* __restrict__ Aq,   // [T][K] int8
    const signed char* __restrict__ Bq,   // [M][K] int8
    const float* __restrict__ mvT,        // [64][4096]
    const float* __restrict__ sxp,        // [T] rowmax/127^2
    float* __restrict__ Y) {
    __shared__ __align__(16) unsigned char lds[65536];

    const int tid  = threadIdx.x;
    const int lane = tid & 63;
    const int wid  = tid >> 6;
    const int wr   = wid >> 2;
    const int wc   = wid & 3;

    const int bid  = blockIdx.x;
    const int swz  = (bid & 7) * 64 + (bid >> 3);   // bijective XCD swizzle
    const int brow = swz >> 4;
    const int bcol = swz & 15;
    const int row0 = brow * 256;
    const int col0 = bcol * 256;

    const int fr  = lane & 15;
    const int fkB = (lane >> 4) * 16;

    f32x4 accf[8][4] = {};
    i32x4 aI[4], bI0[2], bI1[2];
    const i32x4 zero4 = {0, 0, 0, 0};
    float swA[4], swB[4];
    const float* mvp = mvT + col0 + wc * 64 + fr;

    auto issue_seq = [&](int s) {
        int t   = s >> 2;
        int idx = s & 3;
        int buf = t & 1;
        int tc  = t < 64 ? t : 63;
        unsigned regoff = buf * 32768u + idx * 8192u;
        int r = wid * 16 + (lane >> 2);                 // region row 0..127
        int slot = (lane & 3) ^ ((r >> 1) & 3);         // pre-swizzled source
        const signed char* Mat;
        int grow;
        if (idx == 0)      { Mat = Aq; grow = row0 + ((r >> 6) << 7) + (r & 63); }
        else if (idx == 2) { Mat = Aq; grow = row0 + 64 + ((r >> 6) << 7) + (r & 63); }
        else if (idx == 1) { Mat = Bq; grow = col0 + ((r >> 5) << 6) + 32 + (r & 31); }
        else               { Mat = Bq; grow = col0 + ((r >> 5) << 6) + (r & 31); }
        const char* g = (const char*)Mat + (size_t)grow * K_DIM + tc * 64 + slot * 16;
        async_copy16(g, lds + regoff + wid * 1024u);    // linear dest
    };

    // prologue: tile0 r0-r3 + tile1 r0-r2, then vmcnt(3) => tile0 landed
    int seq = 0;
    issue_seq(seq); ++seq;
    issue_seq(seq); ++seq;
    issue_seq(seq); ++seq;
    issue_seq(seq); ++seq;
    issue_seq(seq); ++seq;
    issue_seq(seq); ++seq;
    issue_seq(seq); ++seq;
    #pragma unroll
    for (int ni = 0; ni < 4; ++ni) swA[ni] = mvp[ni * 16];   // scales tile0
    asm volatile("s_waitcnt vmcnt(3)" ::: "memory");
    __builtin_amdgcn_s_barrier();
    asm volatile("" ::: "memory");

    // main loop: 32 iter x 2 K-tiles x 4 phases (snake quad order)
    for (int i = 0; i < 32; ++i) {
        PHASE8(0, 0, 0, 1, 1, 0, swA, swA, -1,        0)
        PHASE8(0, 0, 1, 0, 0, 1, swA, swA, -1,        0)
        PHASE8(0, 1, 1, 1, 0, 0, swA, swB, 2 * i + 1, 0)   // prefetch scales t+1
        PHASE8(0, 1, 0, 0, 0, 0, swA, swA, -1,        1)
        PHASE8(1, 0, 0, 1, 1, 0, swB, swB, -1,        0)
        PHASE8(1, 0, 1, 0, 0, 1, swB, swB, -1,        0)
        PHASE8(1, 1, 1, 1, 0, 0, swB, swA, 2 * i + 2, 0)   // prefetch scales t+2
        PHASE8(1, 1, 0, 0, 0, 0, swB, swB, -1,        1)
    }
    asm volatile("s_waitcnt vmcnt(0)" ::: "memory");

    // epilogue: C/D col=lane&15, row=(lane>>4)*4+reg; y = accf * sx[row]
    const int rb = (lane >> 4) * 4;
    #pragma unroll
    for (int m = 0; m < 8; ++m) {
        const int t0 = row0 + wr * 128 + m * 16 + rb;
        f32x4 sx4 = *reinterpret_cast<const f32x4*>(sxp + t0);
        #pragma unroll
        for (int n = 0; n < 4; ++n)
            #pragma unroll
            for (int r = 0; r < 4; ++r)
                Y[(size_t)(t0 + r) * M_DIM + col0 + wc * 64 + n * 16 + fr] =
                    accf[m][n][r] * sx4[r];
    }
}

// ---------------------------------------------------------------------------
// Fallback m97-style f32->bf16-in-reg GEMM (only if ws too small)
// ---------------------------------------------------------------------------
__global__ __launch_bounds__(256) void gemm_fb(const float* __restrict__ Ap,
                                               const float* __restrict__ Bp,
                                               float* __restrict__ Y) {
    constexpr int BK = 64;
    __shared__ unsigned short lA[128 * BK];
    __shared__ unsigned short lB[128 * BK];

    const int tid  = threadIdx.x;
    const int lane = tid & 63;
    const int wid  = tid >> 6;
    const int wr   = wid >> 1;
    const int wc   = wid & 1;
    const int brow = blockIdx.x >> 5;
    const int bcol = blockIdx.x & 31;
    const int row0 = brow * 128;
    const int col0 = bcol * 128;

    f32x4 acc[4][4] = {};
    const int fr = lane & 15;
    const int fk = (lane >> 4) * 8;
    const int srow = lane >> 3;
    const int scol = (lane & 7) * 8;

    for (int k0 = 0; k0 < K_DIM; k0 += BK) {
        #pragma unroll
        for (int i = 0; i < 4; ++i) {
            const int c = wid * 4 + i;
            const int r = c * 8 + srow;
            const float* g = Ap + (size_t)(row0 + r) * K_DIM + k0 + scol;
            float4 v0 = *reinterpret_cast<const float4*>(g);
            float4 v1 = *reinterpret_cast<const float4*>(g + 4);
            short8 pk;
            pk[0] = (short)f2b(v0.x); pk[1] = (short)f2b(v0.y);
            pk[2] = (short)f2b(v0.z); pk[3] = (short)f2b(v0.w);
            pk[4] = (short)f2b(v1.x); pk[5] = (short)f2b(v1.y);
            pk[6] = (short)f2b(v1.z); pk[7] = (short)f2b(v1.w);
            *reinterpret_cast<short8*>(lA + c * 512 + lane * 8) = pk;
        }
        #pragma unroll
        for (int i = 0; i < 4; ++i) {
            const int c = wid * 4 + i;
            const int r = c * 8 + srow;
            const float* g = Bp + (size_t)(col0 + r) * K_DIM + k0 + scol;
            float4 v0 = *reinterpret_cast<const float4*>(g);
            float4 v1 = *reinterpret_cast<const float4*>(g + 4);
            short8 pk;
            pk[0] = (short)f2b(v0.x); pk[1] = (short)f2b(v0.y);
            pk[2] = (short)f2b(v0.z); pk[3] = (short)f2b(v0.w);
            pk[4] = (short)f2b(v1.x); pk[5] = (short)f2b(v1.y);
            pk[6] = (short)f2b(v1.z); pk[7] = (short)f2b(v1.w);
            *reinterpret_cast<short8*>(lB + c * 512 + lane * 8) = pk;
        }
        __syncthreads();
        #pragma unroll
        for (int kk = 0; kk < BK; kk += 32) {
            short8 af[4], bfr[4];
            #pragma unroll
            for (int m = 0; m < 4; ++m)
                af[m] = *reinterpret_cast<const short8*>(
                    lA + (wr * 64 + m * 16 + fr) * BK + kk + fk);
            #pragma unroll
            for (int n = 0; n < 4; ++n)
                bfr[n] = *reinterpret_cast<const short8*>(
                    lB + (wc * 64 + n * 16 + fr) * BK + kk + fk);
            #pragma unroll
            for (int m = 0; m < 4; ++m)
                #pragma unroll
                for (int n = 0; n < 4; ++n)
                    acc[m][n] = __builtin_amdgcn_mfma_f32_16x16x32_bf16(
                        af[m], bfr[n], acc[m][n], 0, 0, 0);
        }
        __syncthreads();
    }

    const int orow  = row0 + wr * 64;
    const int ocol  = col0 + wc * 64 + fr;
    const int rbase = (lane >> 4) * 4;
    #pragma unroll
    for (int m = 0; m < 4; ++m)
        #pragma unroll
        for (int n = 0; n < 4; ++n)
            #pragma unroll
            for (int r = 0; r < 4; ++r)
                Y[(size_t)(orow + m * 16 + rbase + r) * M_DIM + ocol + n * 16] =
                    acc[m][n][r];
}

// ---------------------------------------------------------------------------
extern "C" void kernel_launch(void* const* d_in, const int* in_sizes, int n_in,
                              void* d_out, int out_size, void* d_ws, size_t ws_size,
                              hipStream_t stream) {
    const float* x   = (const float*)d_in[0];
    const float* w   = (const float*)d_in[1];
    const float* mv  = (const float*)d_in[2];
    const float* lut = (const float*)d_in[3];

    float* y  = (float*)d_out;
    float* qw = y + (size_t)T_DIM * M_DIM;

    const bool full = ws_size >= (50u << 20);   // need ~49.04 MB

    signed char* xq  = (signed char*)d_ws;
    signed char* wqp = xq + (32u << 20);
    float*       mvT = (float*)(xq + (48u << 20));
    float*       sx  = (float*)(xq + (49u << 20));

    prep_w<<<dim3(8192), dim3(256), 0, stream>>>(w, mv, lut, qw,
                                                 full ? wqp : nullptr);
    if (full) {
        prep_x<<<dim3(8192), dim3(512), 0, stream>>>(x, xq, sx);
        mvt_kernel<<<dim3(1024), dim3(256), 0, stream>>>(mv, mvT);
        gemm_i8<<<dim3(512), dim3(512), 0, stream>>>(xq, wqp, mvT, sx, y);
    } else {
        dim3 grid((T_DIM / 128) * (M_DIM / 128));
        gemm_fb<<<grid, dim3(256), 0, stream>>>(x, qw, y);
    }
}

// Round 11
// 212.901 us; speedup vs baseline: 4.7988x; 4.7988x over previous
//
#include <hip/hip_runtime.h>
#include <stdint.h>
#include <stddef.h>

typedef __attribute__((ext_vector_type(8))) short short8;
typedef __attribute__((ext_vector_type(4))) float f32x4;
typedef __attribute__((ext_vector_type(4))) int i32x4;

#define T_DIM 8192
#define M_DIM 4096
#define K_DIM 4096

// f32 -> bf16 round-to-nearest-even (fallback path only)
__device__ __forceinline__ unsigned short f2b(float f) {
    unsigned int u = __builtin_bit_cast(unsigned int, f);
    u += 0x7fffu + ((u >> 16) & 1u);
    return (unsigned short)(u >> 16);
}

__device__ __forceinline__ void async_copy16(const void* g, const void* l) {
    __builtin_amdgcn_global_load_lds(
        (const __attribute__((address_space(1))) unsigned int*)g,
        (__attribute__((address_space(3))) unsigned int*)l,
        16, 0, 0);
}

// ---------------------------------------------------------------------------
// prep_xcw: blocks [0,8192) per-row quantize x -> int8 (scale rowmax/127),
//           sx[row] = rowmax/127^2;
//           blocks [8192,8208) cw[m] = max_t mv[m*64+t]  (per-column w scale).
// ---------------------------------------------------------------------------
__global__ __launch_bounds__(512) void prep_xcw(const float* __restrict__ x,
                                                signed char* __restrict__ xq,
                                                float* __restrict__ sx,
                                                const float* __restrict__ mv,
                                                float* __restrict__ cw) {
    if (blockIdx.x >= 8192) {
        int m = (blockIdx.x - 8192) * 256 + (threadIdx.x & 255);
        if (threadIdx.x < 256) {
            const float4* p = reinterpret_cast<const float4*>(mv + m * 64);
            float mx = 0.0f;
            #pragma unroll
            for (int i = 0; i < 16; ++i) {
                float4 v = p[i];
                mx = fmaxf(mx, fmaxf(fmaxf(v.x, v.y), fmaxf(v.z, v.w)));
            }
            cw[m] = mx;
        }
        return;
    }
    const int row = blockIdx.x;
    const int tid = threadIdx.x;
    const float* xr = x + (size_t)row * K_DIM;

    float4 a = *reinterpret_cast<const float4*>(xr + tid * 8);
    float4 b = *reinterpret_cast<const float4*>(xr + tid * 8 + 4);
    float v[8] = {a.x, a.y, a.z, a.w, b.x, b.y, b.z, b.w};

    float mx = 0.0f;
    #pragma unroll
    for (int e = 0; e < 8; ++e) mx = fmaxf(mx, fabsf(v[e]));
    #pragma unroll
    for (int off = 1; off < 64; off <<= 1)
        mx = fmaxf(mx, __shfl_xor(mx, off, 64));

    __shared__ float wm[8];
    if ((tid & 63) == 0) wm[tid >> 6] = mx;
    __syncthreads();
    float rmax = fmaxf(fmaxf(fmaxf(wm[0], wm[1]), fmaxf(wm[2], wm[3])),
                       fmaxf(fmaxf(wm[4], wm[5]), fmaxf(wm[6], wm[7])));
    float inv = rmax > 0.0f ? 127.0f / rmax : 0.0f;

    unsigned u0 = 0, u1 = 0;
    #pragma unroll
    for (int e = 0; e < 4; ++e) {
        int q = (int)rintf(v[e] * inv);
        q = q > 127 ? 127 : (q < -127 ? -127 : q);
        u0 |= ((unsigned)(q & 255)) << (8 * e);
    }
    #pragma unroll
    for (int e = 0; e < 4; ++e) {
        int q = (int)rintf(v[4 + e] * inv);
        q = q > 127 ? 127 : (q < -127 ? -127 : q);
        u1 |= ((unsigned)(q & 255)) << (8 * e);
    }
    uint2 pk; pk.x = u0; pk.y = u1;
    *reinterpret_cast<uint2*>(xq + (size_t)row * K_DIM + tid * 8) = pk;

    if (tid == 0) sx[row] = rmax / 16129.0f;   // rowmax / 127^2
}

// ---------------------------------------------------------------------------
// prep_w: dequant w -> qw (f32, exact reference path)
//         + wq (int8 = rint(lut*mv*127/cw[row]), per-column scale)
// ---------------------------------------------------------------------------
__global__ void prep_w(const float* __restrict__ w,
                       const float* __restrict__ maxval,
                       const float* __restrict__ lut_g,
                       float* __restrict__ qw,
                       signed char* __restrict__ wq,
                       const float* __restrict__ cw) {
    __shared__ float lut[16];
    if (threadIdx.x < 16) lut[threadIdx.x] = lut_g[threadIdx.x];
    __syncthreads();

    size_t base = ((size_t)blockIdx.x * 256 + threadIdx.x) * 8;
    float mv = maxval[base >> 6];

    float4 w0 = *reinterpret_cast<const float4*>(w + base);
    float4 w1 = *reinterpret_cast<const float4*>(w + base + 4);
    float vin[8] = {w0.x, w0.y, w0.z, w0.w, w1.x, w1.y, w1.z, w1.w};
    float outv[8];
    int   li[8];

    #pragma unroll
    for (int e = 0; e < 8; ++e) {
        float v = vin[e] / mv;
        float bd = fabsf(v - lut[0]);
        int best = 0;
        #pragma unroll
        for (int k = 1; k < 16; ++k) {
            float d = fabsf(v - lut[k]);
            if (d < bd) { bd = d; best = k; }
        }
        outv[e] = lut[best] * mv;
        li[e]   = best;
    }

    float4 o0; o0.x = outv[0]; o0.y = outv[1]; o0.z = outv[2]; o0.w = outv[3];
    float4 o1; o1.x = outv[4]; o1.y = outv[5]; o1.z = outv[6]; o1.w = outv[7];
    *reinterpret_cast<float4*>(qw + base)     = o0;
    *reinterpret_cast<float4*>(qw + base + 4) = o1;

    if (wq != nullptr) {
        float s = 127.0f * mv / cw[base >> 12];   // row = base/4096
        unsigned u0 = 0, u1 = 0;
        #pragma unroll
        for (int e = 0; e < 4; ++e) {
            int q = (int)rintf(lut[li[e]] * s);
            u0 |= ((unsigned)(q & 255)) << (8 * e);
        }
        #pragma unroll
        for (int e = 0; e < 4; ++e) {
            int q = (int)rintf(lut[li[4 + e]] * s);
            u1 |= ((unsigned)(q & 255)) << (8 * e);
        }
        uint2 pk; pk.x = u0; pk.y = u1;
        *reinterpret_cast<uint2*>(wq + base) = pk;
    }
}

// ---------------------------------------------------------------------------
// i8 256x256 GEMM, pure i32 accumulation, RACE-FIXED schedule:
//   acci[t][m] = Σ_k xq*wq;  y = acci * sx[t] * cw[m]   (scales epilogue-only)
// 8 waves (2Mx4N), BK=64, LDS 64KB dbuf, regions 8KB:
//   r0=A(MH0) r1=B(NH1) r2=A(MH1) r3=B(NH0); snake P0..P3.
// Phase = { RD; issue_seq; [vmcnt(3) if P3]; barrier; MFMA }.
// CERTIFICATION (the R10 bug): per-phase RDs run BEFORE the phase barrier, so
// tile-t data must be certified by the barrier of the PRECEDING phase.
// Placing vmcnt(3) BEFORE barrier_P3 makes barrier_P3 certify all waves'
// tile-(t+1) copies retired (vmcnt(3) leaves only the 3 newest = tile-(t+2)
// r0..r2). R10 had vmcnt AFTER barrier_P3 -> cross-wave race, exposed once
// i8 made phases fast (R9's heavy VALU masked it).
// Fragment mfma_i32_16x16x64_i8: lane k0=(lane>>4)*16, 16 consecutive i8
// [HW-verified R9]. LDS swizzle slot=q^((row>>1)&3) [HW-verified R9: 0 confl].
// ---------------------------------------------------------------------------

#define RD_A8(BUF, MH)                                                        \
  { _Pragma("unroll") for (int mi = 0; mi < 4; ++mi) {                        \
        int r_ = wr * 64 + mi * 16 + fr;                                      \
        aI[mi] = *reinterpret_cast<const i32x4*>(                             \
            lds + (BUF) * 32768 + (MH) * 16384 + r_ * 64 +                    \
            (fkB ^ (((r_ >> 1) & 3) << 4)));                                  \
  } }

#define RD_B8(BUF, NH, DST)                                                   \
  { _Pragma("unroll") for (int ni = 0; ni < 2; ++ni) {                        \
        int r_ = wc * 32 + ni * 16 + fr;                                      \
        DST[ni] = *reinterpret_cast<const i32x4*>(                            \
            lds + (BUF) * 32768 + ((NH) ? 8192 : 24576) + r_ * 64 +           \
            (fkB ^ (((r_ >> 1) & 3) << 4)));                                  \
  } }

#define PHASE8(BUF, MH, NH, DO_A, DO_B0, DO_B1, VM)                           \
  {                                                                           \
    if (DO_A)  RD_A8(BUF, MH)                                                 \
    if (DO_B0) RD_B8(BUF, 0, bI0)                                             \
    if (DO_B1) RD_B8(BUF, 1, bI1)                                             \
    issue_seq(seq); ++seq;                                                    \
    if (VM) asm volatile("s_waitcnt vmcnt(3)" ::: "memory");                  \
    asm volatile("" ::: "memory");                                            \
    __builtin_amdgcn_s_barrier();                                             \
    asm volatile("" ::: "memory");                                            \
    __builtin_amdgcn_s_setprio(1);                                            \
    _Pragma("unroll") for (int mi = 0; mi < 4; ++mi)                          \
    _Pragma("unroll") for (int ni = 0; ni < 2; ++ni)                          \
        acci[(MH) * 4 + mi][(NH) * 2 + ni] =                                  \
            __builtin_amdgcn_mfma_i32_16x16x64_i8(                            \
                aI[mi], (NH) ? bI1[ni] : bI0[ni],                             \
                acci[(MH) * 4 + mi][(NH) * 2 + ni], 0, 0, 0);                 \
    __builtin_amdgcn_s_setprio(0);                                            \
  }

__global__ __launch_bounds__(512, 2) void gemm_i8(
    const signed char* __restrict__ Aq,   // [T][K] int8
    const signed char* __restrict__ Bq,   // [M][K] int8
    const float* __restrict__ sxp,        // [T] rowmax/127^2
    const float* __restrict__ cwp,        // [M] per-column w scale
    float* __restrict__ Y) {
    __shared__ __align__(16) unsigned char lds[65536];

    const int tid  = threadIdx.x;
    const int lane = tid & 63;
    const int wid  = tid >> 6;
    const int wr   = wid >> 2;
    const int wc   = wid & 3;

    const int bid  = blockIdx.x;
    const int swz  = (bid & 7) * 64 + (bid >> 3);   // bijective XCD swizzle
    const int brow = swz >> 4;
    const int bcol = swz & 15;
    const int row0 = brow * 256;
    const int col0 = bcol * 256;

    const int fr  = lane & 15;
    const int fkB = (lane >> 4) * 16;

    i32x4 acci[8][4] = {};
    i32x4 aI[4], bI0[2], bI1[2];

    auto issue_seq = [&](int s) {
        int t   = s >> 2;
        int idx = s & 3;
        int buf = t & 1;
        int tc  = t < 64 ? t : 63;
        unsigned regoff = buf * 32768u + idx * 8192u;
        int r = wid * 16 + (lane >> 2);                 // region row 0..127
        int slot = (lane & 3) ^ ((r >> 1) & 3);         // pre-swizzled source
        const signed char* Mat;
        int grow;
        if (idx == 0)      { Mat = Aq; grow = row0 + ((r >> 6) << 7) + (r & 63); }
        else if (idx == 2) { Mat = Aq; grow = row0 + 64 + ((r >> 6) << 7) + (r & 63); }
        else if (idx == 1) { Mat = Bq; grow = col0 + ((r >> 5) << 6) + 32 + (r & 31); }
        else               { Mat = Bq; grow = col0 + ((r >> 5) << 6) + (r & 31); }
        const char* g = (const char*)Mat + (size_t)grow * K_DIM + tc * 64 + slot * 16;
        async_copy16(g, lds + regoff + wid * 1024u);    // linear dest
    };

    // prologue: tile0 r0-r3 + tile1 r0-r2, vmcnt(3) => tile0 landed, barrier
    int seq = 0;
    issue_seq(seq); ++seq;
    issue_seq(seq); ++seq;
    issue_seq(seq); ++seq;
    issue_seq(seq); ++seq;
    issue_seq(seq); ++seq;
    issue_seq(seq); ++seq;
    issue_seq(seq); ++seq;
    asm volatile("s_waitcnt vmcnt(3)" ::: "memory");
    __builtin_amdgcn_s_barrier();
    asm volatile("" ::: "memory");

    // main loop: 32 iter x 2 K-tiles x 4 phases (snake quad order)
    for (int i = 0; i < 32; ++i) {
        PHASE8(0, 0, 0, 1, 1, 0, 0)   // q(0,0): A-MH0(4) + B-NH0(2)
        PHASE8(0, 0, 1, 0, 0, 1, 0)   // q(0,1): B-NH1(2), reuse aI
        PHASE8(0, 1, 1, 1, 0, 0, 0)   // q(1,1): A-MH1(4), reuse bI1
        PHASE8(0, 1, 0, 0, 0, 0, 1)   // q(1,0): reuse aI+bI0; vmcnt(3) BEFORE barrier
        PHASE8(1, 0, 0, 1, 1, 0, 0)
        PHASE8(1, 0, 1, 0, 0, 1, 0)
        PHASE8(1, 1, 1, 1, 0, 0, 0)
        PHASE8(1, 1, 0, 0, 0, 0, 1)
    }
    asm volatile("s_waitcnt vmcnt(0)" ::: "memory");

    // epilogue: C/D col=lane&15, row=(lane>>4)*4+reg; y = acci*sx[t]*cw[m]
    const int rb = (lane >> 4) * 4;
    float cwv[4];
    #pragma unroll
    for (int n = 0; n < 4; ++n) cwv[n] = cwp[col0 + wc * 64 + n * 16 + fr];
    #pragma unroll
    for (int m = 0; m < 8; ++m) {
        const int t0 = row0 + wr * 128 + m * 16 + rb;
        f32x4 sx4 = *reinterpret_cast<const f32x4*>(sxp + t0);
        #pragma unroll
        for (int n = 0; n < 4; ++n)
            #pragma unroll
            for (int r = 0; r < 4; ++r)
                Y[(size_t)(t0 + r) * M_DIM + col0 + wc * 64 + n * 16 + fr] =
                    (float)acci[m][n][r] * sx4[r] * cwv[n];
    }
}

// ---------------------------------------------------------------------------
// Fallback m97-style f32->bf16-in-reg GEMM (only if ws too small)
// ---------------------------------------------------------------------------
__global__ __launch_bounds__(256) void gemm_fb(const float* __restrict__ Ap,
                                               const float* __restrict__ Bp,
                                               float* __restrict__ Y) {
    constexpr int BK = 64;
    __shared__ unsigned short lA[128 * BK];
    __shared__ unsigned short lB[128 * BK];

    const int tid  = threadIdx.x;
    const int lane = tid & 63;
    const int wid  = tid >> 6;
    const int wr   = wid >> 1;
    const int wc   = wid & 1;
    const int brow = blockIdx.x >> 5;
    const int bcol = blockIdx.x & 31;
    const int row0 = brow * 128;
    const int col0 = bcol * 128;

    f32x4 acc[4][4] = {};
    const int fr = lane & 15;
    const int fk = (lane >> 4) * 8;
    const int srow = lane >> 3;
    const int scol = (lane & 7) * 8;

    for (int k0 = 0; k0 < K_DIM; k0 += BK) {
        #pragma unroll
        for (int i = 0; i < 4; ++i) {
            const int c = wid * 4 + i;
            const int r = c * 8 + srow;
            const float* g = Ap + (size_t)(row0 + r) * K_DIM + k0 + scol;
            float4 v0 = *reinterpret_cast<const float4*>(g);
            float4 v1 = *reinterpret_cast<const float4*>(g + 4);
            short8 pk;
            pk[0] = (short)f2b(v0.x); pk[1] = (short)f2b(v0.y);
            pk[2] = (short)f2b(v0.z); pk[3] = (short)f2b(v0.w);
            pk[4] = (short)f2b(v1.x); pk[5] = (short)f2b(v1.y);
            pk[6] = (short)f2b(v1.z); pk[7] = (short)f2b(v1.w);
            *reinterpret_cast<short8*>(lA + c * 512 + lane * 8) = pk;
        }
        #pragma unroll
        for (int i = 0; i < 4; ++i) {
            const int c = wid * 4 + i;
            const int r = c * 8 + srow;
            const float* g = Bp + (size_t)(col0 + r) * K_DIM + k0 + scol;
            float4 v0 = *reinterpret_cast<const float4*>(g);
            float4 v1 = *reinterpret_cast<const float4*>(g + 4);
            short8 pk;
            pk[0] = (short)f2b(v0.x); pk[1] = (short)f2b(v0.y);
            pk[2] = (short)f2b(v0.z); pk[3] = (short)f2b(v0.w);
            pk[4] = (short)f2b(v1.x); pk[5] = (short)f2b(v1.y);
            pk[6] = (short)f2b(v1.z); pk[7] = (short)f2b(v1.w);
            *reinterpret_cast<short8*>(lB + c * 512 + lane * 8) = pk;
        }
        __syncthreads();
        #pragma unroll
        for (int kk = 0; kk < BK; kk += 32) {
            short8 af[4], bfr[4];
            #pragma unroll
            for (int m = 0; m < 4; ++m)
                af[m] = *reinterpret_cast<const short8*>(
                    lA + (wr * 64 + m * 16 + fr) * BK + kk + fk);
            #pragma unroll
            for (int n = 0; n < 4; ++n)
                bfr[n] = *reinterpret_cast<const short8*>(
                    lB + (wc * 64 + n * 16 + fr) * BK + kk + fk);
            #pragma unroll
            for (int m = 0; m < 4; ++m)
                #pragma unroll
                for (int n = 0; n < 4; ++n)
                    acc[m][n] = __builtin_amdgcn_mfma_f32_16x16x32_bf16(
                        af[m], bfr[n], acc[m][n], 0, 0, 0);
        }
        __syncthreads();
    }

    const int orow  = row0 + wr * 64;
    const int ocol  = col0 + wc * 64 + fr;
    const int rbase = (lane >> 4) * 4;
    #pragma unroll
    for (int m = 0; m < 4; ++m)
        #pragma unroll
        for (int n = 0; n < 4; ++n)
            #pragma unroll
            for (int r = 0; r < 4; ++r)
                Y[(size_t)(orow + m * 16 + rbase + r) * M_DIM + ocol + n * 16] =
                    acc[m][n][r];
}

// ---------------------------------------------------------------------------
extern "C" void kernel_launch(void* const* d_in, const int* in_sizes, int n_in,
                              void* d_out, int out_size, void* d_ws, size_t ws_size,
                              hipStream_t stream) {
    const float* x   = (const float*)d_in[0];
    const float* w   = (const float*)d_in[1];
    const float* mv  = (const float*)d_in[2];
    const float* lut = (const float*)d_in[3];

    float* y  = (float*)d_out;
    float* qw = y + (size_t)T_DIM * M_DIM;

    const bool full = ws_size >= (49u << 20);   // need ~48.08 MB

    signed char* xq  = (signed char*)d_ws;                 // 32 MB
    signed char* wqp = xq + (32u << 20);                   // 16 MB
    float*       sx  = (float*)(xq + (48u << 20));         // 32 KB
    float*       cw  = (float*)(xq + (48u << 20) + 65536); // 16 KB

    if (full) {
        prep_xcw<<<dim3(8208), dim3(512), 0, stream>>>(x, xq, sx, mv, cw);
        prep_w<<<dim3(8192), dim3(256), 0, stream>>>(w, mv, lut, qw, wqp, cw);
        gemm_i8<<<dim3(512), dim3(512), 0, stream>>>(xq, wqp, sx, cw, y);
    } else {
        prep_w<<<dim3(8192), dim3(256), 0, stream>>>(w, mv, lut, qw, nullptr, cw);
        dim3 grid((T_DIM / 128) * (M_DIM / 128));
        gemm_fb<<<grid, dim3(256), 0, stream>>>(x, qw, y);
    }
}